// Round 12
// baseline (831.090 us; speedup 1.0000x reference)
//
#include <hip/hip_runtime.h>
#include <hip/hip_cooperative_groups.h>
#include <math.h>

// ChamferLoss on MI355X — round 12: fused cooperative build + query + reduce.
// r11: 455 µs = 170 query + 285 aux over 8 small dependent dispatches (~20 µs
// launch overhead each). This round: zero/count/scan/fill become ONE
// cooperative kernel (grid.sync between phases; transformed points stay in
// registers so fill skips the re-transform); reduce1+reduce2 fuse via the
// deterministic last-block-ticket pattern. query_kernel is verbatim r11
// (measured 170 µs, absmax 0.0). 3 dispatches total.

namespace cg = cooperative_groups;

#define N_PTS 147456          // 384*384
#define N2    (2 * N_PTS)     // both clouds
#define IMG_W 384
#define G     48              // grid edge
#define NC    (G * G * G)     // 110592 cells per cloud
#define NCI   (2 * NC)        // 221184 cells total
#define SCALE 0.48f           // cells per meter: (x+50)*SCALE in [0,48)
#define HC    2.0833333f      // cell width lower bound (conservative)
#define BUILD_BLOCKS 864      // NCI / 256; 864 <= 4 blocks/CU * 256 CUs

// ---- shared geometry (count & fill & query must agree exactly) ----

__device__ __forceinline__ float4 transform_pt(
    int idx, const float* __restrict__ fake, const float* __restrict__ tar,
    int sh, int sw)
{
    int pix = (idx < N_PTS) ? idx : idx - N_PTS;
    int r = pix / IMG_W, c = pix - r * IMG_W;
    float cw = (float)((double)sw / 1285.0 * 360.0);
    float ch = (float)((double)sh / 438.0 * 123.5);
    const float fh = (float)(360.0 * 384.0 / 1285.0);   // fh_crop
    const float fv = (float)(123.5 * 384.0 / 438.0);    // fv_crop
    const float D2R = 0.017453292519943295f;
    float yaw = ((-fh * (float)c) / 384.0f + cw) * D2R;
    float pit = ((-fv * (float)r) / 384.0f + ch) * D2R;
    float sy = sinf(yaw), cy = cosf(yaw);
    float sp = sinf(pit), cp = cosf(pit);
    float d = (idx < N_PTS) ? tar[pix] : fake[pix];   // A=transform(tar), B=transform(fake)
    return make_float4(d * sy * sp, d * cy * sp, d * cp, 0.f);
}

__device__ __forceinline__ int cell_coord(float v) {
    int c = (int)((v + 50.0f) * SCALE);
    return min(max(c, 0), G - 1);
}

__device__ __forceinline__ int cell_of(float x, float y, float z) {
    return (cell_coord(z) * G + cell_coord(y)) * G + cell_coord(x);
}

// ---- fused build: zero -> count -> 3-level scan -> fill (1 dispatch) ----
// 864 blocks x 256. Thread handles points gid and gid+NCI (latter only for
// bid < 288). Points survive in registers across grid.sync() -> fill needs
// no re-transform. Scan semantics identical to r8/r11's scan1/2/3: after
// fill, offc[c] = END offset of cell c.
__global__ __launch_bounds__(256, 4) void build_kernel(
    const float* __restrict__ fake, const float* __restrict__ tar,
    const int* __restrict__ sh_p, const int* __restrict__ sw_p,
    int* __restrict__ offc, int* __restrict__ bsum, int* __restrict__ counter,
    float4* __restrict__ pts)
{
    cg::grid_group grid = cg::this_grid();
    const int tid = threadIdx.x;
    const int bid = blockIdx.x;
    const int gid = bid * 256 + tid;

    // phase 0: zero counts (+ bsum pad + reduce ticket)
    offc[gid] = 0;
    if (bid == 0) {
        #pragma unroll
        for (int i = 0; i < 4; i++) bsum[tid + i * 256] = 0;   // 1024 slots
        if (tid == 0) *counter = 0;
    }
    grid.sync();

    // phase 1: transform (regs) + histogram
    const int sh = *sh_p, sw = *sw_p;
    float4 p0 = transform_pt(gid, fake, tar, sh, sw);
    int b0 = ((gid < N_PTS) ? 0 : NC) + cell_of(p0.x, p0.y, p0.z);
    atomicAdd(&offc[b0], 1);
    const int gid1 = gid + NCI;                  // >= N_PTS always -> cloud B
    float4 p1; int b1 = -1;
    if (gid1 < N2) {
        p1 = transform_pt(gid1, fake, tar, sh, sw);
        b1 = NC + cell_of(p1.x, p1.y, p1.z);
        atomicAdd(&offc[b1], 1);
    }
    grid.sync();

    // phase 2a: per-block exclusive scan in place; block sums -> bsum
    __shared__ int sd[256];
    int c = offc[gid];
    sd[tid] = c;
    __syncthreads();
    for (int o = 1; o < 256; o <<= 1) {
        int v = (tid >= o) ? sd[tid - o] : 0;
        __syncthreads();
        sd[tid] += v;
        __syncthreads();
    }
    offc[gid] = sd[tid] - c;
    if (tid == 255) bsum[bid] = sd[255];
    grid.sync();

    // phase 2b: block 0 exclusive-scans bsum[1024] (864 live, rest zero)
    if (bid == 0) {
        int b4[4]; int s = 0;
        #pragma unroll
        for (int i = 0; i < 4; i++) { b4[i] = bsum[tid * 4 + i]; s += b4[i]; }
        sd[tid] = s;
        __syncthreads();
        for (int o = 1; o < 256; o <<= 1) {
            int v = (tid >= o) ? sd[tid - o] : 0;
            __syncthreads();
            sd[tid] += v;
            __syncthreads();
        }
        int run = sd[tid] - s;
        #pragma unroll
        for (int i = 0; i < 4; i++) { int cc = b4[i]; bsum[tid * 4 + i] = run; run += cc; }
    }
    grid.sync();

    // phase 2c: add block prefix -> global exclusive offsets (= fill cursor)
    offc[gid] += bsum[bid];
    grid.sync();

    // phase 3: fill from registers
    int slot0 = atomicAdd(&offc[b0], 1);
    pts[slot0] = make_float4(p0.x, p0.y, p0.z, 0.f);
    if (b1 >= 0) {
        int slot1 = atomicAdd(&offc[b1], 1);
        pts[slot1] = make_float4(p1.x, p1.y, p1.z, 0.f);
    }
}

// ---- query (verbatim round 11: measured 170 µs, absmax 0.0) ----

#define SCAN_RANGE(LO, HI)                                                  \
    for (int j = (LO) + lane; j < (HI); j += 64) {                          \
        float4 t = pts[j];                                                  \
        float ddx = t.x - qx, ddy = t.y - qy, ddz = t.z - qz;               \
        best = fminf(best, fmaf(ddx, ddx, fmaf(ddy, ddy, ddz * ddz)));      \
    }

#define WAVE_MIN(B)                                                         \
    _Pragma("unroll")                                                       \
    for (int o = 32; o; o >>= 1) (B) = fminf((B), __shfl_xor((B), o, 64));

__global__ __launch_bounds__(256) void query_kernel(
    float4* __restrict__ pts, const int* __restrict__ offc)
{
    const int lane = threadIdx.x & 63;
    const int g = blockIdx.x * 4 + (threadIdx.x >> 6);   // query slot, one/wave
    float4 q = pts[g];                                    // broadcast load
    const float qx = q.x, qy = q.y, qz = q.z;
    const int base = __builtin_amdgcn_readfirstlane((g < N_PTS) ? NC : 0);

    const int cx = __builtin_amdgcn_readfirstlane(cell_coord(qx));
    const int cy = __builtin_amdgcn_readfirstlane(cell_coord(qy));
    const int cz = __builtin_amdgcn_readfirstlane(cell_coord(qz));
    float fx = (qx + 50.0f) * SCALE - (float)cx;          // in [0,1)
    float fy = (qy + 50.0f) * SCALE - (float)cy;
    float fz = (qz + 50.0f) * SCALE - (float)cz;
    float m = fmaxf(fminf(fminf(fminf(fx, 1.0f - fx), fminf(fy, 1.0f - fy)),
                          fminf(fz, 1.0f - fz)), 0.0f);

    float best = __builtin_inff();

    // --- home cell ---
    {
        int c0 = base + (cz * G + cy) * G + cx;
        int lo = c0 ? offc[c0 - 1] : 0;
        int hi = offc[c0];
        SCAN_RANGE(lo, hi)
    }
    WAVE_MIN(best)
    float m2 = m * HC;
    if (best > m2 * m2) {
        // --- s=1: 8 full rows + 2 end cells, each lb-pruned vs uniform best ---
        const float HC2 = HC * HC;
        float bestU = best;                         // uniform after reduce
        #pragma unroll
        for (int dz = -1; dz <= 1; dz++) {
            int iz = cz + dz;
            if (iz < 0 || iz >= G) continue;        // uniform
            float dzl = (dz == 0) ? 0.f : ((dz > 0) ? (1.f - fz) : fz);
            #pragma unroll
            for (int dy = -1; dy <= 1; dy++) {
                int iy = cy + dy;
                if (iy < 0 || iy >= G) continue;
                int rowb = base + (iz * G + iy) * G;
                if (dz == 0 && dy == 0) {           // home row: two end cells
                    if (cx - 1 >= 0 && fx * fx * HC2 < bestU) {
                        int c0 = rowb + cx - 1;
                        int lo = c0 ? offc[c0 - 1] : 0;
                        int hi = offc[c0];
                        SCAN_RANGE(lo, hi)
                    }
                    if (cx + 1 < G && (1.f - fx) * (1.f - fx) * HC2 < bestU) {
                        int c0 = rowb + cx + 1;
                        int lo = c0 ? offc[c0 - 1] : 0;
                        int hi = offc[c0];
                        SCAN_RANGE(lo, hi)
                    }
                } else {                             // full row of 2-3 cells
                    float dyl = (dy == 0) ? 0.f : ((dy > 0) ? (1.f - fy) : fy);
                    if ((dzl * dzl + dyl * dyl) * HC2 < bestU) {
                        int c0 = rowb + max(cx - 1, 0);
                        int c1 = rowb + min(cx + 1, G - 1);
                        int lo = c0 ? offc[c0 - 1] : 0;
                        int hi = offc[c1];
                        SCAN_RANGE(lo, hi)
                    }
                }
            }
        }
        WAVE_MIN(best)
        float bnd1 = (1.0f + m) * HC;
        if (best > bnd1 * bnd1) {
            // --- rare: generic shells from s=2 ---
            for (int s = 2; s <= G; ++s) {
                int zlo = max(cz - s, 0), zhi = min(cz + s, G - 1);
                for (int iz = zlo; iz <= zhi; ++iz) {
                    int adz = iz - cz; adz = (adz < 0) ? -adz : adz;
                    int ylo = max(cy - s, 0), yhi = min(cy + s, G - 1);
                    for (int iy = ylo; iy <= yhi; ++iy) {
                        int ady = iy - cy; ady = (ady < 0) ? -ady : ady;
                        int rowb = base + (iz * G + iy) * G;
                        if (adz == s || ady == s) {
                            int c0 = rowb + max(cx - s, 0);
                            int c1 = rowb + min(cx + s, G - 1);
                            int lo = c0 ? offc[c0 - 1] : 0;
                            int hi = offc[c1];
                            SCAN_RANGE(lo, hi)
                        } else {
                            if (cx - s >= 0) {
                                int c0 = rowb + cx - s;
                                int lo = c0 ? offc[c0 - 1] : 0;
                                int hi = offc[c0];
                                SCAN_RANGE(lo, hi)
                            }
                            if (cx + s <= G - 1) {
                                int c0 = rowb + cx + s;
                                int lo = c0 ? offc[c0 - 1] : 0;
                                int hi = offc[c0];
                                SCAN_RANGE(lo, hi)
                            }
                        }
                    }
                }
                WAVE_MIN(best)
                float bnd = ((float)s + m) * HC;
                if (best <= bnd * bnd) break;
            }
        }
    }

    if (lane == 0) pts[g].w = best;   // readers consume xyz only
}

// ---- fused reduce: 288 partials + last-block final (deterministic) ----
// Arithmetic identical to r11's reduce1 then reduce2 -> bit-identical result.
__global__ __launch_bounds__(256) void reduce_kernel(
    const float4* __restrict__ pts, float* __restrict__ partials,
    int* __restrict__ counter, float* __restrict__ out)
{
    const int tid = threadIdx.x;
    const int basei = blockIdx.x * 1024;
    float s = 0.f;
    #pragma unroll
    for (int t = 0; t < 4; t++) s += pts[basei + t * 256 + tid].w;
    #pragma unroll
    for (int o = 32; o; o >>= 1) s += __shfl_xor(s, o, 64);
    __shared__ float wsum[4];
    __shared__ int lastflag;
    if ((tid & 63) == 0) wsum[tid >> 6] = s;
    __syncthreads();
    if (tid == 0) {
        partials[blockIdx.x] = wsum[0] + wsum[1] + wsum[2] + wsum[3];
        __threadfence();                          // publish partial
        int old = atomicAdd(counter, 1);
        lastflag = (old == 287);
    }
    __syncthreads();
    if (lastflag) {
        __threadfence();                          // acquire all partials
        float s2 = 0.f;
        for (int i = tid; i < 288; i += 256) s2 += partials[i];
        #pragma unroll
        for (int o = 32; o; o >>= 1) s2 += __shfl_xor(s2, o, 64);
        if ((tid & 63) == 0) wsum[tid >> 6] = s2;
        __syncthreads();
        if (tid == 0)
            out[0] = (wsum[0] + wsum[1] + wsum[2] + wsum[3]) / 147456.0f;
    }
}

extern "C" void kernel_launch(void* const* d_in, const int* in_sizes, int n_in,
                              void* d_out, int out_size, void* d_ws, size_t ws_size,
                              hipStream_t stream) {
    const float* fake = (const float*)d_in[0];
    const float* tar  = (const float*)d_in[1];
    const int*   sh_p = (const int*)d_in[2];
    const int*   sw_p = (const int*)d_in[3];
    float* out = (float*)d_out;

    // ws layout: 5.35 MB total (< 5.90 MB proven in rounds 1/4/5)
    int* wsi = (int*)d_ws;
    int*    offc    = wsi;                            // NCI ints
    int*    bsum    = wsi + NCI;                      // 1024 ints
    int*    counter = wsi + NCI + 1024;               // 1 int (+31 pad)
    float*  parts   = (float*)(wsi + NCI + 1056);     // 288 floats
    float4* pts     = (float4*)(wsi + NCI + 1344);    // N2 float4, 16B-aligned

    void* args[] = { (void*)&fake, (void*)&tar, (void*)&sh_p, (void*)&sw_p,
                     (void*)&offc, (void*)&bsum, (void*)&counter, (void*)&pts };
    hipLaunchCooperativeKernel((const void*)build_kernel,
                               dim3(BUILD_BLOCKS), dim3(256), args, 0, stream);
    query_kernel<<<N2 / 4, 256, 0, stream>>>(pts, offc);   // one wave per query
    reduce_kernel<<<N2 / 1024, 256, 0, stream>>>(pts, parts, counter, out);
}

// Round 13
// 504.608 us; speedup vs baseline: 1.6470x; 1.6470x over previous
//
#include <hip/hip_runtime.h>
#include <math.h>

// ChamferLoss on MI355X — round 13: r11 pipeline, 9 -> 6 dispatches with NO
// grid.sync (r12 measured grid.sync at ~120 µs each: build 598 µs, VALU 0.4%).
//  - scan1/2/3 -> ONE decoupled-lookback scan (packed status|value word,
//    warp-parallel lookback; all 864 blocks co-resident -> no deadlock)
//  - reduce1/2 -> r12's proven ticket-fused reduce (bit-identical arithmetic)
//  - zero/count/fill/query verbatim from r11 (455 µs, absmax 0.0; query 170 µs)

#define N_PTS 147456          // 384*384
#define N2    (2 * N_PTS)     // both clouds
#define IMG_W 384
#define G     48              // grid edge
#define NC    (G * G * G)     // 110592 cells per cloud
#define NCI   (2 * NC)        // 221184 cells total
#define SCALE 0.48f           // cells per meter: (x+50)*SCALE in [0,48)
#define HC    2.0833333f      // cell width lower bound (conservative)
#define SCAN_BLOCKS 864       // NCI / 256
#define ZERO_BLOCKS 868       // covers NCI + 1024 (flags + counter + pad)
#define VAL_MASK 0x3FFFFFFF

// ---- shared geometry (count & fill & query must agree exactly) ----

__device__ __forceinline__ float4 transform_pt(
    int idx, const float* __restrict__ fake, const float* __restrict__ tar,
    int sh, int sw)
{
    int pix = (idx < N_PTS) ? idx : idx - N_PTS;
    int r = pix / IMG_W, c = pix - r * IMG_W;
    float cw = (float)((double)sw / 1285.0 * 360.0);
    float ch = (float)((double)sh / 438.0 * 123.5);
    const float fh = (float)(360.0 * 384.0 / 1285.0);   // fh_crop
    const float fv = (float)(123.5 * 384.0 / 438.0);    // fv_crop
    const float D2R = 0.017453292519943295f;
    float yaw = ((-fh * (float)c) / 384.0f + cw) * D2R;
    float pit = ((-fv * (float)r) / 384.0f + ch) * D2R;
    float sy = sinf(yaw), cy = cosf(yaw);
    float sp = sinf(pit), cp = cosf(pit);
    float d = (idx < N_PTS) ? tar[pix] : fake[pix];   // A=transform(tar), B=transform(fake)
    return make_float4(d * sy * sp, d * cy * sp, d * cp, 0.f);
}

__device__ __forceinline__ int cell_coord(float v) {
    int c = (int)((v + 50.0f) * SCALE);
    return min(max(c, 0), G - 1);
}

__device__ __forceinline__ int cell_of(float x, float y, float z) {
    return (cell_coord(z) * G + cell_coord(y)) * G + cell_coord(x);
}

// ---- pipeline ----

__global__ __launch_bounds__(256) void zero_kernel(int* __restrict__ p) {
    p[blockIdx.x * 256 + threadIdx.x] = 0;   // offc + flags + counter + pad
}

__global__ __launch_bounds__(256) void count_kernel(
    const float* __restrict__ fake, const float* __restrict__ tar,
    const int* __restrict__ sh_p, const int* __restrict__ sw_p,
    int* __restrict__ offc)
{
    int idx = blockIdx.x * 256 + threadIdx.x;
    float4 p = transform_pt(idx, fake, tar, *sh_p, *sw_p);
    int bucket = ((idx < N_PTS) ? 0 : NC) + cell_of(p.x, p.y, p.z);
    atomicAdd(&offc[bucket], 1);
}

// Decoupled-lookback scan: offc[NCI] -> global exclusive offsets, in place.
// flag[b] = (status<<30)|value; status 1=aggregate, 2=inclusive prefix.
// Values <= N2 = 294912 < 2^19 -> fits the 30-bit field; one-word atomics
// carry value+status together (no separate fence needed).
__global__ __launch_bounds__(256) void scan_kernel(
    int* __restrict__ offc, int* __restrict__ flag)
{
    __shared__ int sd[256];
    __shared__ int pfx_s;
    const int t = threadIdx.x, b = blockIdx.x;
    const int gid = b * 256 + t;
    int c = offc[gid];
    sd[t] = c;
    __syncthreads();
    for (int o = 1; o < 256; o <<= 1) {
        int v = (t >= o) ? sd[t - o] : 0;
        __syncthreads();
        sd[t] += v;
        __syncthreads();
    }
    const int incl = sd[t];
    const int agg = sd[255];
    if (t == 0) {
        unsigned w = ((b == 0 ? 2u : 1u) << 30) | (unsigned)agg;
        __hip_atomic_store(&flag[b], (int)w, __ATOMIC_RELEASE, __HIP_MEMORY_SCOPE_AGENT);
    }
    if (t < 64) {                              // wave 0: warp-parallel lookback
        const int lane = t;
        int prefix = 0;
        if (b > 0) {
            int iw = b - 1 - lane;             // lane 0 = nearest predecessor
            bool done = false;
            while (!done) {
                int w = (iw >= 0)
                    ? __hip_atomic_load(&flag[iw], __ATOMIC_ACQUIRE, __HIP_MEMORY_SCOPE_AGENT)
                    : (int)(2u << 30);         // before block 0: inclusive 0
                unsigned st = ((unsigned)w) >> 30;
                unsigned long long m2 = __ballot(st == 2u);
                unsigned long long m0 = __ballot(st == 0u);
                int f2 = m2 ? (__ffsll((unsigned long long)m2) - 1) : 64;
                int f0 = m0 ? (__ffsll((unsigned long long)m0) - 1) : 64;
                if (f0 < f2) { __builtin_amdgcn_s_sleep(1); continue; }
                int val = (lane <= f2) ? (w & VAL_MASK) : 0;   // anchor inclusive
                #pragma unroll
                for (int o = 32; o; o >>= 1) val += __shfl_xor(val, o, 64);
                prefix += val;
                if (f2 < 64) done = true;
                else iw -= 64;                 // window slides down
            }
            if (lane == 0) {
                unsigned w2 = (2u << 30) | (unsigned)(prefix + agg);
                __hip_atomic_store(&flag[b], (int)w2, __ATOMIC_RELEASE, __HIP_MEMORY_SCOPE_AGENT);
            }
        }
        if (lane == 0) pfx_s = prefix;
    }
    __syncthreads();
    offc[gid] = pfx_s + incl - c;              // global exclusive offset
}

// scatter points into CSR slots; afterwards offc[c] = END offset of cell c
__global__ __launch_bounds__(256) void fill_kernel(
    const float* __restrict__ fake, const float* __restrict__ tar,
    const int* __restrict__ sh_p, const int* __restrict__ sw_p,
    int* __restrict__ offc, float4* __restrict__ pts)
{
    int idx = blockIdx.x * 256 + threadIdx.x;
    float4 p = transform_pt(idx, fake, tar, *sh_p, *sw_p);
    int bucket = ((idx < N_PTS) ? 0 : NC) + cell_of(p.x, p.y, p.z);
    int slot = atomicAdd(&offc[bucket], 1);
    pts[slot] = make_float4(p.x, p.y, p.z, 0.f);
}

// ---- query (verbatim round 11: measured 170 µs, absmax 0.0) ----

#define SCAN_RANGE(LO, HI)                                                  \
    for (int j = (LO) + lane; j < (HI); j += 64) {                          \
        float4 t = pts[j];                                                  \
        float ddx = t.x - qx, ddy = t.y - qy, ddz = t.z - qz;               \
        best = fminf(best, fmaf(ddx, ddx, fmaf(ddy, ddy, ddz * ddz)));      \
    }

#define WAVE_MIN(B)                                                         \
    _Pragma("unroll")                                                       \
    for (int o = 32; o; o >>= 1) (B) = fminf((B), __shfl_xor((B), o, 64));

__global__ __launch_bounds__(256) void query_kernel(
    float4* __restrict__ pts, const int* __restrict__ offc)
{
    const int lane = threadIdx.x & 63;
    const int g = blockIdx.x * 4 + (threadIdx.x >> 6);   // query slot, one/wave
    float4 q = pts[g];                                    // broadcast load
    const float qx = q.x, qy = q.y, qz = q.z;
    const int base = __builtin_amdgcn_readfirstlane((g < N_PTS) ? NC : 0);

    const int cx = __builtin_amdgcn_readfirstlane(cell_coord(qx));
    const int cy = __builtin_amdgcn_readfirstlane(cell_coord(qy));
    const int cz = __builtin_amdgcn_readfirstlane(cell_coord(qz));
    float fx = (qx + 50.0f) * SCALE - (float)cx;          // in [0,1)
    float fy = (qy + 50.0f) * SCALE - (float)cy;
    float fz = (qz + 50.0f) * SCALE - (float)cz;
    float m = fmaxf(fminf(fminf(fminf(fx, 1.0f - fx), fminf(fy, 1.0f - fy)),
                          fminf(fz, 1.0f - fz)), 0.0f);

    float best = __builtin_inff();

    // --- home cell ---
    {
        int c0 = base + (cz * G + cy) * G + cx;
        int lo = c0 ? offc[c0 - 1] : 0;
        int hi = offc[c0];
        SCAN_RANGE(lo, hi)
    }
    WAVE_MIN(best)
    float m2 = m * HC;
    if (best > m2 * m2) {
        // --- s=1: 8 full rows + 2 end cells, each lb-pruned vs uniform best ---
        const float HC2 = HC * HC;
        float bestU = best;                         // uniform after reduce
        #pragma unroll
        for (int dz = -1; dz <= 1; dz++) {
            int iz = cz + dz;
            if (iz < 0 || iz >= G) continue;        // uniform
            float dzl = (dz == 0) ? 0.f : ((dz > 0) ? (1.f - fz) : fz);
            #pragma unroll
            for (int dy = -1; dy <= 1; dy++) {
                int iy = cy + dy;
                if (iy < 0 || iy >= G) continue;
                int rowb = base + (iz * G + iy) * G;
                if (dz == 0 && dy == 0) {           // home row: two end cells
                    if (cx - 1 >= 0 && fx * fx * HC2 < bestU) {
                        int c0 = rowb + cx - 1;
                        int lo = c0 ? offc[c0 - 1] : 0;
                        int hi = offc[c0];
                        SCAN_RANGE(lo, hi)
                    }
                    if (cx + 1 < G && (1.f - fx) * (1.f - fx) * HC2 < bestU) {
                        int c0 = rowb + cx + 1;
                        int lo = c0 ? offc[c0 - 1] : 0;
                        int hi = offc[c0];
                        SCAN_RANGE(lo, hi)
                    }
                } else {                             // full row of 2-3 cells
                    float dyl = (dy == 0) ? 0.f : ((dy > 0) ? (1.f - fy) : fy);
                    if ((dzl * dzl + dyl * dyl) * HC2 < bestU) {
                        int c0 = rowb + max(cx - 1, 0);
                        int c1 = rowb + min(cx + 1, G - 1);
                        int lo = c0 ? offc[c0 - 1] : 0;
                        int hi = offc[c1];
                        SCAN_RANGE(lo, hi)
                    }
                }
            }
        }
        WAVE_MIN(best)
        float bnd1 = (1.0f + m) * HC;
        if (best > bnd1 * bnd1) {
            // --- rare: generic shells from s=2 ---
            for (int s = 2; s <= G; ++s) {
                int zlo = max(cz - s, 0), zhi = min(cz + s, G - 1);
                for (int iz = zlo; iz <= zhi; ++iz) {
                    int adz = iz - cz; adz = (adz < 0) ? -adz : adz;
                    int ylo = max(cy - s, 0), yhi = min(cy + s, G - 1);
                    for (int iy = ylo; iy <= yhi; ++iy) {
                        int ady = iy - cy; ady = (ady < 0) ? -ady : ady;
                        int rowb = base + (iz * G + iy) * G;
                        if (adz == s || ady == s) {
                            int c0 = rowb + max(cx - s, 0);
                            int c1 = rowb + min(cx + s, G - 1);
                            int lo = c0 ? offc[c0 - 1] : 0;
                            int hi = offc[c1];
                            SCAN_RANGE(lo, hi)
                        } else {
                            if (cx - s >= 0) {
                                int c0 = rowb + cx - s;
                                int lo = c0 ? offc[c0 - 1] : 0;
                                int hi = offc[c0];
                                SCAN_RANGE(lo, hi)
                            }
                            if (cx + s <= G - 1) {
                                int c0 = rowb + cx + s;
                                int lo = c0 ? offc[c0 - 1] : 0;
                                int hi = offc[c0];
                                SCAN_RANGE(lo, hi)
                            }
                        }
                    }
                }
                WAVE_MIN(best)
                float bnd = ((float)s + m) * HC;
                if (best <= bnd * bnd) break;
            }
        }
    }

    if (lane == 0) pts[g].w = best;   // readers consume xyz only
}

// ---- fused reduce (verbatim r12: proven, deterministic) ----
__global__ __launch_bounds__(256) void reduce_kernel(
    const float4* __restrict__ pts, float* __restrict__ partials,
    int* __restrict__ counter, float* __restrict__ out)
{
    const int tid = threadIdx.x;
    const int basei = blockIdx.x * 1024;
    float s = 0.f;
    #pragma unroll
    for (int t = 0; t < 4; t++) s += pts[basei + t * 256 + tid].w;
    #pragma unroll
    for (int o = 32; o; o >>= 1) s += __shfl_xor(s, o, 64);
    __shared__ float wsum[4];
    __shared__ int lastflag;
    if ((tid & 63) == 0) wsum[tid >> 6] = s;
    __syncthreads();
    if (tid == 0) {
        partials[blockIdx.x] = wsum[0] + wsum[1] + wsum[2] + wsum[3];
        __threadfence();                          // publish partial
        int old = atomicAdd(counter, 1);
        lastflag = (old == 287);
    }
    __syncthreads();
    if (lastflag) {
        __threadfence();                          // acquire all partials
        float s2 = 0.f;
        for (int i = tid; i < 288; i += 256) s2 += partials[i];
        #pragma unroll
        for (int o = 32; o; o >>= 1) s2 += __shfl_xor(s2, o, 64);
        if ((tid & 63) == 0) wsum[tid >> 6] = s2;
        __syncthreads();
        if (tid == 0)
            out[0] = (wsum[0] + wsum[1] + wsum[2] + wsum[3]) / 147456.0f;
    }
}

extern "C" void kernel_launch(void* const* d_in, const int* in_sizes, int n_in,
                              void* d_out, int out_size, void* d_ws, size_t ws_size,
                              hipStream_t stream) {
    const float* fake = (const float*)d_in[0];
    const float* tar  = (const float*)d_in[1];
    const int*   sh_p = (const int*)d_in[2];
    const int*   sw_p = (const int*)d_in[3];
    float* out = (float*)d_out;

    // ws layout: 5,608,576 B = 5.35 MB (< 5.90 MB proven)
    int* wsi = (int*)d_ws;
    int*    offc    = wsi;                            // NCI ints
    int*    flags   = wsi + NCI;                      // 864 ints (lookback)
    int*    counter = wsi + NCI + 864;                // 1 int (reduce ticket)
    float*  parts   = (float*)(wsi + NCI + 1024);     // 288 floats
    float4* pts     = (float4*)(wsi + NCI + 1312);    // N2 float4, 16B-aligned

    zero_kernel<<<ZERO_BLOCKS, 256, 0, stream>>>(wsi);                       // offc+flags+counter
    count_kernel<<<N2 / 256, 256, 0, stream>>>(fake, tar, sh_p, sw_p, offc);
    scan_kernel<<<SCAN_BLOCKS, 256, 0, stream>>>(offc, flags);
    fill_kernel<<<N2 / 256, 256, 0, stream>>>(fake, tar, sh_p, sw_p, offc, pts);
    query_kernel<<<N2 / 4, 256, 0, stream>>>(pts, offc);   // one wave per query
    reduce_kernel<<<N2 / 1024, 256, 0, stream>>>(pts, parts, counter, out);
}